// Round 1
// baseline (399.265 us; speedup 1.0000x reference)
//
#include <hip/hip_runtime.h>
#include <cstdint>

// GRU recurrent autoencoder, MI355X persistent-MFMA implementation.
// B=2048, T=128, X=38, H=128, 3H=384. fp32 I/O, fp16 MFMA operands,
// fp32 accumulation + fp32 recurrent state (in registers).
//
// Grid 256 WGs (1/CU) x 512 threads (8 waves, 2/SIMD). Each WG owns 8 batch
// rows and runs all 256 sequential steps. Wave w owns gate tiles
// r: j in [16w,16w+16), z: [128+16w,...), n: [256+16w,...): the (r,z,n)
// triple for the same 16 h-columns lives in the same lanes -> gate epilogue
// is pure register math. Weight B-fragments persist in VGPRs (enc weights
// reloaded as dec weights after the encoder phase).

#define T_SEQ 128
#define X_DIM 38
#define H_DIM 128
#define B_TOT 2048
#define BT    8
#define HS    136   // h-state row stride in halfs (padded: 2-way banks, free)
#define OS    72    // o-state row stride in halfs
#define XSR   40    // x stage row stride in halfs (cols 38,39 stay zero)

typedef _Float16 half8 __attribute__((ext_vector_type(8)));
typedef float    f32x4 __attribute__((ext_vector_type(4)));

__device__ __forceinline__ float fast_sigmoid(float x) {
    return __builtin_amdgcn_rcpf(1.0f + __expf(-x));
}
__device__ __forceinline__ float fast_tanh(float x) {
    // tanh(x) = 1 - 2/(exp(2x)+1); inf-safe at both ends.
    return 1.0f - 2.0f * __builtin_amdgcn_rcpf(1.0f + __expf(2.0f * x));
}

__global__ __launch_bounds__(512, 2)
void rae_gru_kernel(const float* __restrict__ x,
                    const float* __restrict__ eWih, const float* __restrict__ eWhh,
                    const float* __restrict__ ebih, const float* __restrict__ ebhh,
                    const float* __restrict__ dWih, const float* __restrict__ dWhh,
                    const float* __restrict__ dbih, const float* __restrict__ dbhh,
                    const float* __restrict__ linW, const float* __restrict__ linb,
                    float* __restrict__ out)
{
    __shared__ _Float16 hbuf[2 * 16 * HS];   // 8704 B, double-buffered h (fp16)
    __shared__ _Float16 obuf[2 * 16 * OS];   // 4608 B, double-buffered o (fp16)
    __shared__ _Float16 sbuf[2 * 8 * XSR];   // 1280 B, x stage (enc prefetch)

    const int tid  = threadIdx.x;
    const int wv   = tid >> 6;     // wave 0..7
    const int ln   = tid & 63;
    const int quad = ln >> 4;      // 0..3  (k-group for A/B frags; row-group for C/D)
    const int mrow = ln & 15;      // A: m-row / B: n-col / C: col
    const int b0   = blockIdx.x * BT;
    const int xr   = mrow & 7;     // clamp A-row reads for padding rows 8..15

    // ---- zero LDS state (rows 8..15 / cols >=38 must stay zero forever) ----
    for (int i = tid; i < 2 * 16 * HS;  i += 512) hbuf[i] = (_Float16)0.0f;
    for (int i = tid; i < 2 * 16 * OS;  i += 512) obuf[i] = (_Float16)0.0f;
    for (int i = tid; i < 2 * 8 * XSR;  i += 512) sbuf[i] = (_Float16)0.0f;

    // prestage x[:, t=0, :] into sbuf[0]: wave w stages batch row w, lane=col
    if (ln < X_DIM)
        sbuf[wv * XSR + ln] =
            (_Float16)x[((size_t)(b0 + wv) * T_SEQ + 0) * X_DIM + ln];
    __syncthreads();

    half8 zero8;
    #pragma unroll
    for (int e = 0; e < 8; ++e) zero8[e] = (_Float16)0.0f;

    // ---- persistent weight fragments (per wave: r,z,n tile triple) ----
    half8 wh[3][4];          // Whh B-frags: [gate][k-chunk of 32]
    half8 wi[3][2];          // Wih B-frags: [gate][k-chunk], K padded 38->64
    float bgh[3], bgi[3];    // biases folded into accumulator init
    const int jcol[3] = { wv * 16 + mrow,
                          H_DIM + wv * 16 + mrow,
                          2 * H_DIM + wv * 16 + mrow };

    auto load_rnn_weights = [&](const float* __restrict__ Wih,
                                const float* __restrict__ Whh,
                                const float* __restrict__ bih,
                                const float* __restrict__ bhh) {
        #pragma unroll
        for (int p = 0; p < 3; ++p) {
            const float* wr = Whh + (size_t)jcol[p] * H_DIM;
            #pragma unroll
            for (int c = 0; c < 4; ++c) {
                const int kb = c * 32 + quad * 8;
                half8 v;
                #pragma unroll
                for (int e = 0; e < 8; ++e) v[e] = (_Float16)wr[kb + e];
                wh[p][c] = v;
            }
            const float* wir = Wih + (size_t)jcol[p] * X_DIM;
            #pragma unroll
            for (int c = 0; c < 2; ++c) {
                const int kb = c * 32 + quad * 8;
                half8 v;
                #pragma unroll
                for (int e = 0; e < 8; ++e) {
                    const int k = kb + e;
                    v[e] = (k < X_DIM) ? (_Float16)wir[k] : (_Float16)0.0f;
                }
                wi[p][c] = v;
            }
        }
        bgh[0] = bih[jcol[0]] + bhh[jcol[0]];   // r: all biases into gh acc
        bgh[1] = bih[jcol[1]] + bhh[jcol[1]];   // z
        bgh[2] = bhh[jcol[2]];                  // n: bhh with gh (r-gated term)
        bgi[0] = 0.0f; bgi[1] = 0.0f;
        bgi[2] = bih[jcol[2]];                  // n: bih with gi
    };

    float hold[4] = {0.0f, 0.0f, 0.0f, 0.0f};  // fp32 h state, lane-resident

    // one GRU step: h' = (1-z)n + z h, given gi A-frags (x or o_prev)
    auto gru_step = [&](const _Float16* __restrict__ hrd,
                        _Float16* __restrict__ hwr,
                        const half8 xa0, const half8 xa1) {
        half8 ha[4];
        #pragma unroll
        for (int c = 0; c < 4; ++c)
            ha[c] = *(const half8*)&hrd[mrow * HS + c * 32 + quad * 8];

        f32x4 agh[3], agi[3];
        #pragma unroll
        for (int p = 0; p < 3; ++p) {
            f32x4 a = { bgh[p], bgh[p], bgh[p], bgh[p] };
            #pragma unroll
            for (int c = 0; c < 4; ++c)
                a = __builtin_amdgcn_mfma_f32_16x16x32_f16(ha[c], wh[p][c], a, 0, 0, 0);
            agh[p] = a;
            f32x4 g = { bgi[p], bgi[p], bgi[p], bgi[p] };
            g = __builtin_amdgcn_mfma_f32_16x16x32_f16(xa0, wi[p][0], g, 0, 0, 0);
            g = __builtin_amdgcn_mfma_f32_16x16x32_f16(xa1, wi[p][1], g, 0, 0, 0);
            agi[p] = g;
        }
        #pragma unroll
        for (int i = 0; i < 4; ++i) {
            const float r = fast_sigmoid(agh[0][i] + agi[0][i]);
            const float z = fast_sigmoid(agh[1][i] + agi[1][i]);
            const float n = fast_tanh(agi[2][i] + r * agh[2][i]);
            const float h = (1.0f - z) * n + z * hold[i];
            hold[i] = h;
            const int row = quad * 4 + i;
            if (row < BT)   // rows 8..15 are batch padding: never written
                hwr[row * HS + wv * 16 + mrow] = (_Float16)h;
        }
    };

    // ================= encoder =================
    load_rnn_weights(eWih, eWhh, ebih, ebhh);
    #pragma unroll 1
    for (int t = 0; t < T_SEQ; ++t) {
        // prefetch next step's x column early (hidden under MFMA)
        float xnext = 0.0f;
        const bool pf = (t + 1 < T_SEQ) && (ln < X_DIM);
        if (pf) xnext = x[((size_t)(b0 + wv) * T_SEQ + (t + 1)) * X_DIM + ln];

        const _Float16* hrd = hbuf + (t & 1) * (16 * HS);
        _Float16*       hwr = hbuf + ((t & 1) ^ 1) * (16 * HS);
        const _Float16* sb  = sbuf + (t & 1) * (8 * XSR);

        half8 xa0 = *(const half8*)&sb[xr * XSR + quad * 8];
        half8 xa1 = zero8;
        if (quad == 0) xa1 = *(const half8*)&sb[xr * XSR + 32]; // k=32..39 (38,39 zero)

        gru_step(hrd, hwr, xa0, xa1);

        if (pf) sbuf[((t + 1) & 1) * (8 * XSR) + wv * XSR + ln] = (_Float16)xnext;
        __syncthreads();
    }

    // ================= decoder =================
    load_rnn_weights(dWih, dWhh, dbih, dbhh);   // overwrite enc weights in regs
    half8 wl[4];
    float lb = 0.0f;
    {
        const int n  = wv * 16 + mrow;
        const bool nv = (wv < 3) && (n < X_DIM);
        const float* lr = linW + (size_t)(nv ? n : 0) * H_DIM;
        #pragma unroll
        for (int c = 0; c < 4; ++c) {
            const int kb = c * 32 + quad * 8;
            half8 v;
            #pragma unroll
            for (int e = 0; e < 8; ++e)
                v[e] = nv ? (_Float16)lr[kb + e] : (_Float16)0.0f;
            wl[c] = v;
        }
        if (nv) lb = linb[n];
    }

    #pragma unroll 1
    for (int t = 0; t < T_SEQ; ++t) {
        const int pb = t & 1;
        const _Float16* hrd = hbuf + pb * (16 * HS);
        _Float16*       hwr = hbuf + (pb ^ 1) * (16 * HS);
        const _Float16* opr = obuf + pb * (16 * OS);
        _Float16*       owr = obuf + (pb ^ 1) * (16 * OS);

        // o_prev A-frags (t=0: GO = zeros from init)
        half8 oa0 = *(const half8*)&opr[mrow * OS + quad * 8];
        half8 oa1 = *(const half8*)&opr[mrow * OS + 32 + quad * 8];

        gru_step(hrd, hwr, oa0, oa1);
        __syncthreads();   // h' complete before projection reads all k

        // output projection o = h' @ linW^T + lin_b   (waves 0..2, N=48 tile)
        if (wv < 3) {
            half8 hf[4];
            #pragma unroll
            for (int c = 0; c < 4; ++c)
                hf[c] = *(const half8*)&hwr[mrow * HS + c * 32 + quad * 8];
            f32x4 al = {0.0f, 0.0f, 0.0f, 0.0f};
            #pragma unroll
            for (int c = 0; c < 4; ++c)
                al = __builtin_amdgcn_mfma_f32_16x16x32_f16(hf[c], wl[c], al, 0, 0, 0);
            const int n = wv * 16 + mrow;
            if (n < X_DIM) {
                #pragma unroll
                for (int i = 0; i < 4; ++i) {
                    const int row = quad * 4 + i;
                    if (row < BT) {
                        const float o = al[i] + lb;
                        owr[row * OS + n] = (_Float16)o;  // fed back next step
                        out[((size_t)(b0 + row) * T_SEQ + t) * X_DIM + n] = o;
                    }
                }
            }
        }
        __syncthreads();   // o visible before next step's gi reads
    }
}

extern "C" void kernel_launch(void* const* d_in, const int* in_sizes, int n_in,
                              void* d_out, int out_size, void* d_ws, size_t ws_size,
                              hipStream_t stream) {
    (void)in_sizes; (void)n_in; (void)d_ws; (void)ws_size; (void)out_size;
    const float* x    = (const float*)d_in[0];
    const float* eWih = (const float*)d_in[1];
    const float* eWhh = (const float*)d_in[2];
    const float* ebih = (const float*)d_in[3];
    const float* ebhh = (const float*)d_in[4];
    const float* dWih = (const float*)d_in[5];
    const float* dWhh = (const float*)d_in[6];
    const float* dbih = (const float*)d_in[7];
    const float* dbhh = (const float*)d_in[8];
    const float* linW = (const float*)d_in[9];
    const float* linb = (const float*)d_in[10];
    float* out = (float*)d_out;

    rae_gru_kernel<<<dim3(B_TOT / BT), dim3(512), 0, stream>>>(
        x, eWih, eWhh, ebih, ebhh, dWih, dWhh, dbih, dbhh, linW, linb, out);
}